// Round 6
// baseline (684.612 us; speedup 1.0000x reference)
//
#include <hip/hip_runtime.h>
#include <hip/hip_fp16.h>
#include <math.h>

#define N_NODES 20000
#define N_EDGES 640000
#define IN_CH 64
#define EDGE_DIM 16
#define HID 128
#define N_LAYERS 3
#define N_GRAPHS 128
#define PLANE ((size_t)N_NODES * 64)

typedef _Float16 h2 __attribute__((ext_vector_type(2)));
typedef unsigned long long ull;

__device__ inline float fdot2f(h2 a, h2 b, float c) {
#if __has_builtin(__builtin_amdgcn_fdot2)
    return __builtin_amdgcn_fdot2(a, b, c, false);
#else
    float d;
    asm("v_dot2_f32_f16 %0, %1, %2, %3" : "=v"(d) : "v"(a), "v"(b), "v"(c));
    return d;
#endif
}
__device__ inline h2 asH2(unsigned u) { union { unsigned u; h2 h; } x; x.u = u; return x.h; }
__device__ inline unsigned packh2(float a, float b) {
    union { __half2 h; unsigned u; } x; x.h = __floats2half2_rn(a, b); return x.u;
}

// ---------------- CSR build ----------------

__global__ void hist_kernel(const int* __restrict__ dst, int* __restrict__ deg, int n) {
    int i = blockIdx.x * blockDim.x + threadIdx.x;
    if (i < n) atomicAdd(&deg[dst[i]], 1);
}

__global__ __launch_bounds__(1024) void scan_kernel(const int* __restrict__ deg,
                                                    int* __restrict__ rowptr) {
    __shared__ int buf[1024];
    const int t = threadIdx.x;
    constexpr int PER = 20;
    const int base = t * PER;
    int loc[PER];
    int s = 0;
    #pragma unroll
    for (int i = 0; i < PER; i++) {
        int v = (base + i < N_NODES) ? deg[base + i] : 0;
        loc[i] = s; s += v;
    }
    buf[t] = s;
    __syncthreads();
    for (int off = 1; off < 1024; off <<= 1) {
        int x = (t >= off) ? buf[t - off] : 0;
        __syncthreads();
        buf[t] += x;
        __syncthreads();
    }
    const int excl = (t == 0) ? 0 : buf[t - 1];
    #pragma unroll
    for (int i = 0; i < PER; i++)
        if (base + i < N_NODES) rowptr[base + i] = excl + loc[i];
    if (t == 1023) rowptr[N_NODES] = buf[1023];
}

// scatter: assign CSR slot, write src index AND fp16 edge_attr directly into slot order
__global__ __launch_bounds__(256) void scatter_kernel(const int* __restrict__ ei,
                                                      const float* __restrict__ ea,
                                                      const int* __restrict__ rowptr,
                                                      int* __restrict__ cursor,
                                                      int* __restrict__ csr_src,
                                                      __half* __restrict__ eattr, int n) {
    int e = blockIdx.x * blockDim.x + threadIdx.x;
    if (e < n) {
        int d = ei[N_EDGES + e];
        int pos = atomicAdd(&cursor[d], 1);
        int slot = rowptr[d] + pos;
        csr_src[slot] = ei[e];
        const float4* s4 = (const float4*)(ea + (size_t)e * EDGE_DIM);
        const float4 a = s4[0], b = s4[1], c = s4[2], dd = s4[3];
        uint4 p0, p1;
        p0.x = packh2(a.x, a.y);  p0.y = packh2(a.z, a.w);
        p0.z = packh2(b.x, b.y);  p0.w = packh2(b.z, b.w);
        p1.x = packh2(c.x, c.y);  p1.y = packh2(c.z, c.w);
        p1.z = packh2(dd.x, dd.y); p1.w = packh2(dd.z, dd.w);
        uint4* o = (uint4*)(eattr + (size_t)slot * EDGE_DIM);
        o[0] = p0; o[1] = p1;
    }
}

// pack W1e: pk[l][ch][j] = half2(W1e[2j][ch], W1e[2j+1][ch])  -> 2 uint4 loads per lane
__global__ __launch_bounds__(128) void prep_w1e(const float* __restrict__ msg_w1,
                                                unsigned* __restrict__ pk) {
    const int l = blockIdx.x, c = threadIdx.x;
    const float* W1e = msg_w1 + (size_t)l * (HID + EDGE_DIM) * HID + HID * HID;
    #pragma unroll
    for (int j = 0; j < 8; j++)
        pk[((size_t)l * HID + c) * 8 + j] = packh2(W1e[(2 * j) * HID + c], W1e[(2 * j + 1) * HID + c]);
}

// ---------------- combined W2u = msg_w2 @ upd_w_bottom, all layers (f32) ----------------

__global__ __launch_bounds__(128) void w2u_all(const float* __restrict__ msg_w2,
                                               const float* __restrict__ msg_b2,
                                               const float* __restrict__ upd_w,
                                               float* __restrict__ W2u,
                                               float* __restrict__ b2u) {
    __shared__ float row[HID];
    const int t = threadIdx.x;
    const int l = blockIdx.x / 129, d = blockIdx.x % 129;
    const float* w2 = msg_w2 + (size_t)l * HID * HID;
    const float* wu_bot = upd_w + (size_t)l * 2 * HID * HID + HID * HID;
    const float* src = (d < HID) ? (w2 + d * HID) : (msg_b2 + l * HID);
    row[t] = src[t];
    __syncthreads();
    float acc = 0.f;
    for (int k = 0; k < HID; k++) acc += row[k] * wu_bot[k * HID + t];
    if (d < HID) W2u[(size_t)l * HID * HID + d * HID + t] = acc;
    else b2u[l * HID + t] = acc;
}

// pack update weights to half2 pairs along K: pkU[(l*3+m)][kk][c][q], k2 = kk*4+q
// m: 0 = upd_w top (Wt), 1 = W2u, 2 = next-layer msg_w1 node part (EMIT)
__global__ __launch_bounds__(128) void pack_upd(const float* __restrict__ upd_w,
                                                const float* __restrict__ W2u_all,
                                                const float* __restrict__ msg_w1,
                                                unsigned* __restrict__ pkU) {
    const int id = blockIdx.x;       // 9 blocks
    const int l = id / 3, m = id % 3, c = threadIdx.x;
    unsigned* dst = pkU + (size_t)id * 16 * 128 * 4;
    const float* src;
    if (m == 0) src = upd_w + (size_t)l * 2 * HID * HID;
    else if (m == 1) src = W2u_all + (size_t)l * HID * HID;
    else { if (l == 2) return; src = msg_w1 + (size_t)(l + 1) * (HID + EDGE_DIM) * HID; }
    for (int k2 = 0; k2 < 64; k2++) {
        const int kk = k2 >> 2, q = k2 & 3;
        dst[((size_t)kk * 128 + c) * 4 + q] = packh2(src[(2 * k2) * HID + c],
                                                     src[(2 * k2 + 1) * HID + c]);
    }
}

// ---------------- node GEMM: out[N,128] = in[N,KIN] @ W[KIN,128] + bias ----------------
// HALF_OUT writes channel-plane layout: plane p = ch>>6, [node*64 + (ch&63)]

template<int KIN, bool HALF_OUT>
__global__ __launch_bounds__(128) void gemm_nodes(const float* __restrict__ in,
                                                  const float* __restrict__ W,
                                                  const float* __restrict__ bias,
                                                  void* __restrict__ outp) {
    constexpr int NPB = 16;
    __shared__ __align__(16) float a[NPB * KIN];
    const int t = threadIdx.x;
    const int node0 = blockIdx.x * NPB;
    const float* src = in + (size_t)node0 * KIN;
    #pragma unroll
    for (int i = t * 4; i < NPB * KIN; i += 512)
        *(float4*)(a + i) = *(const float4*)(src + i);
    __syncthreads();
    float acc[NPB];
    const float bv = bias[t];
    #pragma unroll
    for (int n = 0; n < NPB; n++) acc[n] = bv;
    for (int k = 0; k < KIN; k += 4) {
        const float w0 = W[(k + 0) * HID + t];
        const float w1 = W[(k + 1) * HID + t];
        const float w2 = W[(k + 2) * HID + t];
        const float w3 = W[(k + 3) * HID + t];
        #pragma unroll
        for (int n = 0; n < NPB; n++) {
            const float4 av = *(const float4*)(a + n * KIN + k);
            acc[n] += av.x * w0 + av.y * w1 + av.z * w2 + av.w * w3;
        }
    }
    if (HALF_OUT) {
        __half* o = (__half*)outp + (size_t)(t >> 6) * PLANE + (size_t)node0 * 64 + (t & 63);
        #pragma unroll
        for (int n = 0; n < NPB; n++) o[n * 64] = __float2half(acc[n]);
    } else {
        float* o = (float*)outp + (size_t)node0 * HID + t;
        #pragma unroll
        for (int n = 0; n < NPB; n++) o[n * HID] = acc[n];
    }
}

// -------- edge aggregate, channel-split planes + XCD steering --------
// pass = (bid>>2)&1 (XCDs 0-3 -> pass0, 4-7 -> pass1, assuming XCD = bid%8 round-robin).
// One wave per (node, pass): lane l owns channel pass*64+l. npart plane (2.5MB) stays
// L2-resident per XCD; eattr/csr are nontemporal streams.

__global__ __launch_bounds__(256) void edge_aggr5(const __half* __restrict__ npart,
                                                  const unsigned* __restrict__ w1epk,
                                                  const __half* __restrict__ eattr,
                                                  const int* __restrict__ rowptr,
                                                  const int* __restrict__ csr_src,
                                                  float* __restrict__ r) {
    const int bid = blockIdx.x;
    const int t = threadIdx.x, w = t >> 6, l = t & 63;
    const int pass = (bid >> 2) & 1;
    const int node = (((bid >> 3) << 2) + (bid & 3)) * 4 + w;
    const int ch = pass * 64 + l;
    h2 wk[8];
    {
        const uint4* wp = (const uint4*)(w1epk + (size_t)ch * 8);
        const uint4 w0 = wp[0], w1 = wp[1];
        wk[0] = asH2(w0.x); wk[1] = asH2(w0.y); wk[2] = asH2(w0.z); wk[3] = asH2(w0.w);
        wk[4] = asH2(w1.x); wk[5] = asH2(w1.y); wk[6] = asH2(w1.z); wk[7] = asH2(w1.w);
    }
    const __half* np = npart + (size_t)pass * PLANE;
    const int beg = rowptr[node], end = rowptr[node + 1];
    float acc = 0.f;
    int i = beg;
    for (; i + 4 <= end; i += 4) {
        int s[4];
        #pragma unroll
        for (int j = 0; j < 4; j++) s[j] = __builtin_nontemporal_load(csr_src + i + j);
        float hv[4];
        #pragma unroll
        for (int j = 0; j < 4; j++) hv[j] = __half2float(np[(size_t)s[j] * 64 + l]);
        #pragma unroll
        for (int j = 0; j < 4; j++) {
            union { ull v[4]; h2 h[8]; } ea;
            const ull* p = (const ull*)(eattr + (size_t)(i + j) * EDGE_DIM);
            ea.v[0] = __builtin_nontemporal_load(p + 0);
            ea.v[1] = __builtin_nontemporal_load(p + 1);
            ea.v[2] = __builtin_nontemporal_load(p + 2);
            ea.v[3] = __builtin_nontemporal_load(p + 3);
            float z = hv[j];
            #pragma unroll
            for (int k = 0; k < 8; k++) z = fdot2f(ea.h[k], wk[k], z);
            acc += fmaxf(z, 0.f);
        }
    }
    for (; i < end; i++) {
        const int s0 = __builtin_nontemporal_load(csr_src + i);
        const float hv0 = __half2float(np[(size_t)s0 * 64 + l]);
        union { ull v[4]; h2 h[8]; } ea;
        const ull* p = (const ull*)(eattr + (size_t)i * EDGE_DIM);
        ea.v[0] = __builtin_nontemporal_load(p + 0);
        ea.v[1] = __builtin_nontemporal_load(p + 1);
        ea.v[2] = __builtin_nontemporal_load(p + 2);
        ea.v[3] = __builtin_nontemporal_load(p + 3);
        float z = hv0;
        #pragma unroll
        for (int k = 0; k < 8; k++) z = fdot2f(ea.h[k], wk[k], z);
        acc += fmaxf(z, 0.f);
    }
    r[(size_t)node * HID + ch] = acc;
}

// ------- fused update + LayerNorm + relu + residual via fp16 dot2; optional npart EMIT -------

template<bool EMIT>
__global__ __launch_bounds__(128) void update_nodes2(float* __restrict__ h,
                                                     const float* __restrict__ r,
                                                     const int* __restrict__ deg,
                                                     const unsigned* __restrict__ pkL,
                                                     const float* __restrict__ ub,
                                                     const float* __restrict__ b2u,
                                                     const float* __restrict__ lng,
                                                     const float* __restrict__ lnb,
                                                     const float* __restrict__ nb1,
                                                     __half* __restrict__ npart) {
    constexpr int NPB = 8;
    __shared__ unsigned sh2[NPB * 64];
    __shared__ unsigned sr2[NPB * 64];
    __shared__ float2 psum[2][NPB];
    const int t = threadIdx.x;
    const int node0 = blockIdx.x * NPB;
    const float4* h4 = (const float4*)(h + (size_t)node0 * HID);
    const float4* r4 = (const float4*)(r + (size_t)node0 * HID);
    #pragma unroll
    for (int i = t; i < NPB * HID / 4; i += 128) {
        const float4 v = h4[i];
        sh2[2 * i] = packh2(v.x, v.y); sh2[2 * i + 1] = packh2(v.z, v.w);
        const float4 u = r4[i];
        sr2[2 * i] = packh2(u.x, u.y); sr2[2 * i + 1] = packh2(u.z, u.w);
    }
    __syncthreads();
    const unsigned* pkWt = pkL;
    const unsigned* pkW2 = pkL + 16 * 128 * 4;
    float acc[NPB];
    const float ubv = ub[t], b2uv = b2u[t];
    #pragma unroll
    for (int n = 0; n < NPB; n++) acc[n] = ubv + (float)deg[node0 + n] * b2uv;
    for (int kk = 0; kk < 16; kk++) {
        const uint4 wt = *(const uint4*)(pkWt + ((size_t)kk * 128 + t) * 4);
        const uint4 w2 = *(const uint4*)(pkW2 + ((size_t)kk * 128 + t) * 4);
        #pragma unroll
        for (int n = 0; n < NPB; n++) {
            const uint4 ha = *(const uint4*)&sh2[n * 64 + kk * 4];
            const uint4 ra = *(const uint4*)&sr2[n * 64 + kk * 4];
            acc[n] = fdot2f(asH2(ha.x), asH2(wt.x), acc[n]);
            acc[n] = fdot2f(asH2(ha.y), asH2(wt.y), acc[n]);
            acc[n] = fdot2f(asH2(ha.z), asH2(wt.z), acc[n]);
            acc[n] = fdot2f(asH2(ha.w), asH2(wt.w), acc[n]);
            acc[n] = fdot2f(asH2(ra.x), asH2(w2.x), acc[n]);
            acc[n] = fdot2f(asH2(ra.y), asH2(w2.y), acc[n]);
            acc[n] = fdot2f(asH2(ra.z), asH2(w2.z), acc[n]);
            acc[n] = fdot2f(asH2(ra.w), asH2(w2.w), acc[n]);
        }
    }
    #pragma unroll
    for (int n = 0; n < NPB; n++) acc[n] = fmaxf(acc[n], 0.f);
    // LN stats: shuffle reduce across 128 threads (2 waves)
    {
        float s[NPB], ss[NPB];
        #pragma unroll
        for (int n = 0; n < NPB; n++) { s[n] = acc[n]; ss[n] = acc[n] * acc[n]; }
        for (int off = 1; off < 64; off <<= 1) {
            #pragma unroll
            for (int n = 0; n < NPB; n++) {
                s[n] += __shfl_xor(s[n], off);
                ss[n] += __shfl_xor(ss[n], off);
            }
        }
        if ((t & 63) == 0) {
            const int wv = t >> 6;
            #pragma unroll
            for (int n = 0; n < NPB; n++) psum[wv][n] = make_float2(s[n], ss[n]);
        }
    }
    __syncthreads();
    const float g = lng[t], b = lnb[t];
    float vnew[NPB];
    #pragma unroll
    for (int n = 0; n < NPB; n++) {
        const float s = psum[0][n].x + psum[1][n].x;
        const float ss = psum[0][n].y + psum[1][n].y;
        const float mu = s * (1.f / HID);
        const float var = ss * (1.f / HID) - mu * mu;
        const float rs = rsqrtf(var + 1e-5f);
        const float hold = __half2float(((const __half*)&sh2[n * 64 + (t >> 1)])[t & 1]);
        const float v = fmaxf((acc[n] - mu) * rs * g + b, 0.f) + hold;
        vnew[n] = v;
        h[(size_t)(node0 + n) * HID + t] = v;
    }
    if (EMIT) {
        __syncthreads();                 // everyone done reading old sh2
        #pragma unroll
        for (int n = 0; n < NPB; n++) {
            const float vx = __shfl_xor(vnew[n], 1);
            if (!(t & 1)) sh2[n * 64 + (t >> 1)] = packh2(vnew[n], vx);
        }
        __syncthreads();
        const unsigned* pkN = pkL + 2 * 16 * 128 * 4;
        float acc2[NPB];
        const float nbv = nb1[t];
        #pragma unroll
        for (int n = 0; n < NPB; n++) acc2[n] = nbv;
        for (int kk = 0; kk < 16; kk++) {
            const uint4 wn = *(const uint4*)(pkN + ((size_t)kk * 128 + t) * 4);
            #pragma unroll
            for (int n = 0; n < NPB; n++) {
                const uint4 ha = *(const uint4*)&sh2[n * 64 + kk * 4];
                acc2[n] = fdot2f(asH2(ha.x), asH2(wn.x), acc2[n]);
                acc2[n] = fdot2f(asH2(ha.y), asH2(wn.y), acc2[n]);
                acc2[n] = fdot2f(asH2(ha.z), asH2(wn.z), acc2[n]);
                acc2[n] = fdot2f(asH2(ha.w), asH2(wn.w), acc2[n]);
            }
        }
        __half* o = npart + (size_t)(t >> 6) * PLANE + (size_t)node0 * 64 + (t & 63);
        #pragma unroll
        for (int n = 0; n < NPB; n++) o[n * 64] = __float2half(acc2[n]);
    }
}

// ---------------- fused pooling + readout (batch sorted -> segment scan) ----------------

__global__ __launch_bounds__(128) void pool_readout(const float* __restrict__ h,
                                                    const int* __restrict__ batch,
                                                    const float* __restrict__ w1,
                                                    const float* __restrict__ b1,
                                                    const float* __restrict__ w2,
                                                    const float* __restrict__ b2,
                                                    float* __restrict__ out) {
    __shared__ int sbe[2];
    __shared__ float g[2 * HID];
    __shared__ float red[2];
    const int t = threadIdx.x, gi = blockIdx.x;
    if (t < 2) {
        const int target = gi + t;
        int lo = 0, hi = N_NODES;
        while (lo < hi) { int m = (lo + hi) >> 1; if (batch[m] < target) lo = m + 1; else hi = m; }
        sbe[t] = lo;
    }
    __syncthreads();
    const int beg = sbe[0], end = sbe[1];
    float sum = 0.f, mx = -INFINITY;
    int n = beg;
    for (; n + 4 <= end; n += 4) {
        const float v0 = h[(size_t)(n + 0) * HID + t];
        const float v1 = h[(size_t)(n + 1) * HID + t];
        const float v2 = h[(size_t)(n + 2) * HID + t];
        const float v3 = h[(size_t)(n + 3) * HID + t];
        sum += v0 + v1 + v2 + v3;
        mx = fmaxf(mx, fmaxf(fmaxf(v0, v1), fmaxf(v2, v3)));
    }
    for (; n < end; n++) { const float v = h[(size_t)n * HID + t]; sum += v; mx = fmaxf(mx, v); }
    const float c = fmaxf((float)(end - beg), 1.f);
    g[t] = sum / c;
    g[HID + t] = mx;
    __syncthreads();
    float acc = b1[t];
    for (int k = 0; k < 2 * HID; k++) acc += g[k] * w1[k * HID + t];
    float s = fmaxf(acc, 0.f) * w2[t];
    s += __shfl_down(s, 32); s += __shfl_down(s, 16); s += __shfl_down(s, 8);
    s += __shfl_down(s, 4);  s += __shfl_down(s, 2);  s += __shfl_down(s, 1);
    if ((t & 63) == 0) red[t >> 6] = s;
    __syncthreads();
    if (t == 0) out[gi] = red[0] + red[1] + b2[0];
}

// ---------------- launch ----------------

extern "C" void kernel_launch(void* const* d_in, const int* in_sizes, int n_in,
                              void* d_out, int out_size, void* d_ws, size_t ws_size,
                              hipStream_t stream) {
    const float* x           = (const float*)d_in[0];
    const int*   edge_index  = (const int*)  d_in[1];
    const float* edge_attr   = (const float*)d_in[2];
    const int*   batch       = (const int*)  d_in[3];
    const float* node_proj_w = (const float*)d_in[4];
    const float* node_proj_b = (const float*)d_in[5];
    const float* msg_w1      = (const float*)d_in[6];
    const float* msg_b1      = (const float*)d_in[7];
    const float* msg_w2      = (const float*)d_in[8];
    const float* msg_b2      = (const float*)d_in[9];
    const float* upd_w       = (const float*)d_in[10];
    const float* upd_b       = (const float*)d_in[11];
    const float* ln_g        = (const float*)d_in[12];
    const float* ln_b        = (const float*)d_in[13];
    const float* ffn_w1      = (const float*)d_in[14];
    const float* ffn_b1      = (const float*)d_in[15];
    const float* ffn_w2      = (const float*)d_in[16];
    const float* ffn_b2      = (const float*)d_in[17];
    float* out = (float*)d_out;

    char* ws = (char*)d_ws;
    size_t off = 0;
    auto alloc = [&](size_t b) -> char* {
        char* p = ws + off;
        off = (off + b + 255) & ~(size_t)255;
        return p;
    };
    float*    h        = (float*)alloc((size_t)N_NODES * HID * 4);
    __half*   npart_h  = (__half*)alloc(2 * PLANE * 2);             // two channel planes
    float*    r        = (float*)alloc((size_t)N_NODES * HID * 4);
    float*    W2u_all  = (float*)alloc((size_t)N_LAYERS * HID * HID * 4);
    float*    b2u_all  = (float*)alloc((size_t)N_LAYERS * HID * 4);
    unsigned* w1epk    = (unsigned*)alloc((size_t)N_LAYERS * HID * 8 * 4);
    unsigned* pkU      = (unsigned*)alloc((size_t)9 * 16 * 128 * 4 * 4);
    int*      rowptr   = (int*)alloc((N_NODES + 1) * 4);
    int*      deg      = (int*)alloc((size_t)N_NODES * 4 * 2);      // deg + cursor contiguous
    int*      cursor   = deg + N_NODES;
    int*      csr_src  = (int*)alloc((size_t)N_EDGES * 4);
    __half*   eattr_h  = (__half*)alloc((size_t)N_EDGES * EDGE_DIM * 2);
    (void)in_sizes; (void)n_in; (void)out_size; (void)ws_size;

    // CSR build (per call; ws is re-poisoned each launch)
    hipMemsetAsync(deg, 0, (size_t)N_NODES * 4 * 2, stream);
    hist_kernel<<<(N_EDGES + 255) / 256, 256, 0, stream>>>(edge_index + N_EDGES, deg, N_EDGES);
    scan_kernel<<<1, 1024, 0, stream>>>(deg, rowptr);
    scatter_kernel<<<(N_EDGES + 255) / 256, 256, 0, stream>>>(edge_index, edge_attr, rowptr,
                                                              cursor, csr_src, eattr_h, N_EDGES);
    prep_w1e<<<N_LAYERS, 128, 0, stream>>>(msg_w1, w1epk);
    w2u_all<<<N_LAYERS * 129, 128, 0, stream>>>(msg_w2, msg_b2, upd_w, W2u_all, b2u_all);
    pack_upd<<<9, 128, 0, stream>>>(upd_w, W2u_all, msg_w1, pkU);
    // h = x @ node_proj_w + b
    gemm_nodes<IN_CH, false><<<N_NODES / 16, 128, 0, stream>>>(x, node_proj_w, node_proj_b, h);
    // layer-0 npart (plane layout)
    gemm_nodes<HID, true><<<N_NODES / 16, 128, 0, stream>>>(h, msg_w1, msg_b1, npart_h);

    for (int l = 0; l < N_LAYERS; l++) {
        edge_aggr5<<<N_NODES / 2, 256, 0, stream>>>(npart_h, w1epk + (size_t)l * HID * 8,
                                                    eattr_h, rowptr, csr_src, r);
        const unsigned* pkL = pkU + (size_t)(l * 3) * 16 * 128 * 4;
        if (l + 1 < N_LAYERS)
            update_nodes2<true><<<N_NODES / 8, 128, 0, stream>>>(
                h, r, deg, pkL, upd_b + l * HID, b2u_all + l * HID,
                ln_g + l * HID, ln_b + l * HID, msg_b1 + (size_t)(l + 1) * HID, npart_h);
        else
            update_nodes2<false><<<N_NODES / 8, 128, 0, stream>>>(
                h, r, deg, pkL, upd_b + l * HID, b2u_all + l * HID,
                ln_g + l * HID, ln_b + l * HID, msg_b1, npart_h);
    }

    pool_readout<<<N_GRAPHS, 128, 0, stream>>>(h, batch, ffn_w1, ffn_b1, ffn_w2, ffn_b2, out);
}

// Round 7
// 528.815 us; speedup vs baseline: 1.2946x; 1.2946x over previous
//
#include <hip/hip_runtime.h>
#include <hip/hip_fp16.h>
#include <math.h>

#define N_NODES 20000
#define N_EDGES 640000
#define IN_CH 64
#define EDGE_DIM 16
#define HID 128
#define N_LAYERS 3
#define N_GRAPHS 128

typedef _Float16 h2 __attribute__((ext_vector_type(2)));
typedef unsigned long long ull;

__device__ inline float fdot2f(h2 a, h2 b, float c) {
#if __has_builtin(__builtin_amdgcn_fdot2)
    return __builtin_amdgcn_fdot2(a, b, c, false);
#else
    float d;
    asm("v_dot2_f32_f16 %0, %1, %2, %3" : "=v"(d) : "v"(a), "v"(b), "v"(c));
    return d;
#endif
}
__device__ inline h2 asH2(unsigned u) { union { unsigned u; h2 h; } x; x.u = u; return x.h; }
__device__ inline unsigned packh2(float a, float b) {
    union { __half2 h; unsigned u; } x; x.h = __floats2half2_rn(a, b); return x.u;
}

// ---------------- CSR build ----------------

__global__ void hist_kernel(const int* __restrict__ dst, int* __restrict__ deg, int n) {
    int i = blockIdx.x * blockDim.x + threadIdx.x;
    if (i < n) atomicAdd(&deg[dst[i]], 1);
}

__global__ __launch_bounds__(1024) void scan_kernel(const int* __restrict__ deg,
                                                    int* __restrict__ rowptr) {
    __shared__ int buf[1024];
    const int t = threadIdx.x;
    constexpr int PER = 20;
    const int base = t * PER;
    int loc[PER];
    int s = 0;
    #pragma unroll
    for (int i = 0; i < PER; i++) {
        int v = (base + i < N_NODES) ? deg[base + i] : 0;
        loc[i] = s; s += v;
    }
    buf[t] = s;
    __syncthreads();
    for (int off = 1; off < 1024; off <<= 1) {
        int x = (t >= off) ? buf[t - off] : 0;
        __syncthreads();
        buf[t] += x;
        __syncthreads();
    }
    const int excl = (t == 0) ? 0 : buf[t - 1];
    #pragma unroll
    for (int i = 0; i < PER; i++)
        if (base + i < N_NODES) rowptr[base + i] = excl + loc[i];
    if (t == 1023) rowptr[N_NODES] = buf[1023];
}

// scatter: assign CSR slot, write src index AND fp16 edge_attr directly into slot order
__global__ __launch_bounds__(256) void scatter_kernel(const int* __restrict__ ei,
                                                      const float* __restrict__ ea,
                                                      const int* __restrict__ rowptr,
                                                      int* __restrict__ cursor,
                                                      int* __restrict__ csr_src,
                                                      __half* __restrict__ eattr, int n) {
    int e = blockIdx.x * blockDim.x + threadIdx.x;
    if (e < n) {
        int d = ei[N_EDGES + e];
        int pos = atomicAdd(&cursor[d], 1);
        int slot = rowptr[d] + pos;
        csr_src[slot] = ei[e];
        const float4* s4 = (const float4*)(ea + (size_t)e * EDGE_DIM);
        const float4 a = s4[0], b = s4[1], c = s4[2], dd = s4[3];
        uint4 p0, p1;
        p0.x = packh2(a.x, a.y);  p0.y = packh2(a.z, a.w);
        p0.z = packh2(b.x, b.y);  p0.w = packh2(b.z, b.w);
        p1.x = packh2(c.x, c.y);  p1.y = packh2(c.z, c.w);
        p1.z = packh2(dd.x, dd.y); p1.w = packh2(dd.z, dd.w);
        uint4* o = (uint4*)(eattr + (size_t)slot * EDGE_DIM);
        o[0] = p0; o[1] = p1;
    }
}

// pack W1e channel-major: pk[l][c][j] = half2(W1e[2j][c], W1e[2j+1][c])
__global__ __launch_bounds__(128) void prep_w1e(const float* __restrict__ msg_w1,
                                                unsigned* __restrict__ pk) {
    const int l = blockIdx.x, c = threadIdx.x;
    const float* W1e = msg_w1 + (size_t)l * (HID + EDGE_DIM) * HID + HID * HID;
    #pragma unroll
    for (int j = 0; j < 8; j++)
        pk[((size_t)l * HID + c) * 8 + j] = packh2(W1e[(2 * j) * HID + c], W1e[(2 * j + 1) * HID + c]);
}

// ---------------- combined W2u = msg_w2 @ upd_w_bottom, all layers (f32) ----------------

__global__ __launch_bounds__(128) void w2u_all(const float* __restrict__ msg_w2,
                                               const float* __restrict__ msg_b2,
                                               const float* __restrict__ upd_w,
                                               float* __restrict__ W2u,
                                               float* __restrict__ b2u) {
    __shared__ float row[HID];
    const int t = threadIdx.x;
    const int l = blockIdx.x / 129, d = blockIdx.x % 129;
    const float* w2 = msg_w2 + (size_t)l * HID * HID;
    const float* wu_bot = upd_w + (size_t)l * 2 * HID * HID + HID * HID;
    const float* src = (d < HID) ? (w2 + d * HID) : (msg_b2 + l * HID);
    row[t] = src[t];
    __syncthreads();
    float acc = 0.f;
    for (int k = 0; k < HID; k++) acc += row[k] * wu_bot[k * HID + t];
    if (d < HID) W2u[(size_t)l * HID * HID + d * HID + t] = acc;
    else b2u[l * HID + t] = acc;
}

// pack update weights to half2 pairs along K: pkU[(l*3+m)][kk][c][q], k2 = kk*4+q
// m: 0 = upd_w top (Wt), 1 = W2u, 2 = next-layer msg_w1 node part (EMIT)
__global__ __launch_bounds__(128) void pack_upd(const float* __restrict__ upd_w,
                                                const float* __restrict__ W2u_all,
                                                const float* __restrict__ msg_w1,
                                                unsigned* __restrict__ pkU) {
    const int id = blockIdx.x;       // 9 blocks
    const int l = id / 3, m = id % 3, c = threadIdx.x;
    unsigned* dst = pkU + (size_t)id * 16 * 128 * 4;
    const float* src;
    if (m == 0) src = upd_w + (size_t)l * 2 * HID * HID;
    else if (m == 1) src = W2u_all + (size_t)l * HID * HID;
    else { if (l == 2) return; src = msg_w1 + (size_t)(l + 1) * (HID + EDGE_DIM) * HID; }
    for (int k2 = 0; k2 < 64; k2++) {
        const int kk = k2 >> 2, q = k2 & 3;
        dst[((size_t)kk * 128 + c) * 4 + q] = packh2(src[(2 * k2) * HID + c],
                                                     src[(2 * k2 + 1) * HID + c]);
    }
}

// ------- fused node-proj + layer-0 npart: h = x@Wp+bp ; npart = h@mw1+mb1 (fp16) -------

__global__ __launch_bounds__(128) void gemm_fused(const float* __restrict__ x,
                                                  const float* __restrict__ Wp,
                                                  const float* __restrict__ bp,
                                                  const float* __restrict__ mw1,
                                                  const float* __restrict__ mb1,
                                                  float* __restrict__ h,
                                                  __half* __restrict__ npart) {
    constexpr int NPB = 16;
    __shared__ __align__(16) float a[NPB * IN_CH];
    __shared__ __align__(16) float sh[NPB * HID];
    const int t = threadIdx.x;
    const int node0 = blockIdx.x * NPB;
    const float* src = x + (size_t)node0 * IN_CH;
    #pragma unroll
    for (int i = t * 4; i < NPB * IN_CH; i += 512)
        *(float4*)(a + i) = *(const float4*)(src + i);
    __syncthreads();
    float acc[NPB];
    const float bv = bp[t];
    #pragma unroll
    for (int n = 0; n < NPB; n++) acc[n] = bv;
    for (int k = 0; k < IN_CH; k += 4) {
        const float w0 = Wp[(k + 0) * HID + t];
        const float w1 = Wp[(k + 1) * HID + t];
        const float w2 = Wp[(k + 2) * HID + t];
        const float w3 = Wp[(k + 3) * HID + t];
        #pragma unroll
        for (int n = 0; n < NPB; n++) {
            const float4 av = *(const float4*)(a + n * IN_CH + k);
            acc[n] += av.x * w0 + av.y * w1 + av.z * w2 + av.w * w3;
        }
    }
    float* o = h + (size_t)node0 * HID + t;
    #pragma unroll
    for (int n = 0; n < NPB; n++) { o[n * HID] = acc[n]; sh[n * HID + t] = acc[n]; }
    __syncthreads();
    float acc2[NPB];
    const float nbv = mb1[t];
    #pragma unroll
    for (int n = 0; n < NPB; n++) acc2[n] = nbv;
    for (int k = 0; k < HID; k += 4) {
        const float w0 = mw1[(k + 0) * HID + t];
        const float w1 = mw1[(k + 1) * HID + t];
        const float w2 = mw1[(k + 2) * HID + t];
        const float w3 = mw1[(k + 3) * HID + t];
        #pragma unroll
        for (int n = 0; n < NPB; n++) {
            const float4 hv = *(const float4*)(sh + n * HID + k);
            acc2[n] += hv.x * w0 + hv.y * w1 + hv.z * w2 + hv.w * w3;
        }
    }
    __half* op = npart + (size_t)node0 * HID + t;
    #pragma unroll
    for (int n = 0; n < NPB; n++) op[n * HID] = __float2half(acc2[n]);
}

// -------- edge aggregate: r[n] = sum_{e: dst=n} relu(npart[src] + ea@W1e) --------
// One wave per node, 8-deep gather pipeline for memory-level parallelism.

__device__ inline void edge_mac(const __half* __restrict__ eattr, size_t i, unsigned hvu,
                                const h2* wk0, const h2* wk1, float& acc0, float& acc1) {
    union { uint4 u; h2 h[4]; } ea, eb;
    const uint4* ep = (const uint4*)(eattr + i * EDGE_DIM);
    ea.u = ep[0]; eb.u = ep[1];
    const h2 hv = asH2(hvu);
    float z0 = (float)hv.x, z1 = (float)hv.y;
    #pragma unroll
    for (int k = 0; k < 4; k++) {
        z0 = fdot2f(ea.h[k], wk0[k], z0);
        z1 = fdot2f(ea.h[k], wk1[k], z1);
    }
    #pragma unroll
    for (int k = 0; k < 4; k++) {
        z0 = fdot2f(eb.h[k], wk0[4 + k], z0);
        z1 = fdot2f(eb.h[k], wk1[4 + k], z1);
    }
    acc0 += fmaxf(z0, 0.f);
    acc1 += fmaxf(z1, 0.f);
}

__global__ __launch_bounds__(256) void edge_aggr6(const __half* __restrict__ npart,
                                                  const unsigned* __restrict__ w1epk,
                                                  const __half* __restrict__ eattr,
                                                  const int* __restrict__ rowptr,
                                                  const int* __restrict__ csr_src,
                                                  float* __restrict__ r) {
    const int t = threadIdx.x;
    const int w = t >> 6, l = t & 63;
    const int node = blockIdx.x * 4 + w;
    h2 wk0[8], wk1[8];
    {
        const uint4* wp = (const uint4*)(w1epk + (size_t)(2 * l) * 8);
        const uint4 a0 = wp[0], a1 = wp[1], b0 = wp[2], b1 = wp[3];
        wk0[0] = asH2(a0.x); wk0[1] = asH2(a0.y); wk0[2] = asH2(a0.z); wk0[3] = asH2(a0.w);
        wk0[4] = asH2(a1.x); wk0[5] = asH2(a1.y); wk0[6] = asH2(a1.z); wk0[7] = asH2(a1.w);
        wk1[0] = asH2(b0.x); wk1[1] = asH2(b0.y); wk1[2] = asH2(b0.z); wk1[3] = asH2(b0.w);
        wk1[4] = asH2(b1.x); wk1[5] = asH2(b1.y); wk1[6] = asH2(b1.z); wk1[7] = asH2(b1.w);
    }
    const int beg = rowptr[node], end = rowptr[node + 1];
    float acc0 = 0.f, acc1 = 0.f;
    int i = beg;
    for (; i + 8 <= end; i += 8) {
        int s[8];
        #pragma unroll
        for (int j = 0; j < 8; j++) s[j] = csr_src[i + j];
        unsigned hvu[8];
        #pragma unroll
        for (int j = 0; j < 8; j++)
            hvu[j] = *(const unsigned*)(npart + (size_t)s[j] * HID + 2 * l);
        #pragma unroll
        for (int j = 0; j < 8; j++)
            edge_mac(eattr, (size_t)(i + j), hvu[j], wk0, wk1, acc0, acc1);
    }
    for (; i < end; i++) {
        const int s0 = csr_src[i];
        const unsigned hvu = *(const unsigned*)(npart + (size_t)s0 * HID + 2 * l);
        edge_mac(eattr, (size_t)i, hvu, wk0, wk1, acc0, acc1);
    }
    *(float2*)(r + (size_t)node * HID + 2 * l) = make_float2(acc0, acc1);
}

// ------- fused update + LayerNorm + relu + residual via fp16 dot2; optional npart EMIT -------

template<bool EMIT>
__global__ __launch_bounds__(128) void update_nodes2(float* __restrict__ h,
                                                     const float* __restrict__ r,
                                                     const int* __restrict__ deg,
                                                     const unsigned* __restrict__ pkL,
                                                     const float* __restrict__ ub,
                                                     const float* __restrict__ b2u,
                                                     const float* __restrict__ lng,
                                                     const float* __restrict__ lnb,
                                                     const float* __restrict__ nb1,
                                                     __half* __restrict__ npart) {
    constexpr int NPB = 8;
    __shared__ unsigned sh2[NPB * 64];
    __shared__ unsigned sr2[NPB * 64];
    __shared__ float2 psum[2][NPB];
    const int t = threadIdx.x;
    const int node0 = blockIdx.x * NPB;
    const float4* h4 = (const float4*)(h + (size_t)node0 * HID);
    const float4* r4 = (const float4*)(r + (size_t)node0 * HID);
    #pragma unroll
    for (int i = t; i < NPB * HID / 4; i += 128) {
        const float4 v = h4[i];
        sh2[2 * i] = packh2(v.x, v.y); sh2[2 * i + 1] = packh2(v.z, v.w);
        const float4 u = r4[i];
        sr2[2 * i] = packh2(u.x, u.y); sr2[2 * i + 1] = packh2(u.z, u.w);
    }
    __syncthreads();
    const unsigned* pkWt = pkL;
    const unsigned* pkW2 = pkL + 16 * 128 * 4;
    float acc[NPB];
    const float ubv = ub[t], b2uv = b2u[t];
    #pragma unroll
    for (int n = 0; n < NPB; n++) acc[n] = ubv + (float)deg[node0 + n] * b2uv;
    for (int kk = 0; kk < 16; kk++) {
        const uint4 wt = *(const uint4*)(pkWt + ((size_t)kk * 128 + t) * 4);
        const uint4 w2 = *(const uint4*)(pkW2 + ((size_t)kk * 128 + t) * 4);
        #pragma unroll
        for (int n = 0; n < NPB; n++) {
            const uint4 ha = *(const uint4*)&sh2[n * 64 + kk * 4];
            const uint4 ra = *(const uint4*)&sr2[n * 64 + kk * 4];
            acc[n] = fdot2f(asH2(ha.x), asH2(wt.x), acc[n]);
            acc[n] = fdot2f(asH2(ha.y), asH2(wt.y), acc[n]);
            acc[n] = fdot2f(asH2(ha.z), asH2(wt.z), acc[n]);
            acc[n] = fdot2f(asH2(ha.w), asH2(wt.w), acc[n]);
            acc[n] = fdot2f(asH2(ra.x), asH2(w2.x), acc[n]);
            acc[n] = fdot2f(asH2(ra.y), asH2(w2.y), acc[n]);
            acc[n] = fdot2f(asH2(ra.z), asH2(w2.z), acc[n]);
            acc[n] = fdot2f(asH2(ra.w), asH2(w2.w), acc[n]);
        }
    }
    #pragma unroll
    for (int n = 0; n < NPB; n++) acc[n] = fmaxf(acc[n], 0.f);
    {
        float s[NPB], ss[NPB];
        #pragma unroll
        for (int n = 0; n < NPB; n++) { s[n] = acc[n]; ss[n] = acc[n] * acc[n]; }
        for (int off = 1; off < 64; off <<= 1) {
            #pragma unroll
            for (int n = 0; n < NPB; n++) {
                s[n] += __shfl_xor(s[n], off);
                ss[n] += __shfl_xor(ss[n], off);
            }
        }
        if ((t & 63) == 0) {
            const int wv = t >> 6;
            #pragma unroll
            for (int n = 0; n < NPB; n++) psum[wv][n] = make_float2(s[n], ss[n]);
        }
    }
    __syncthreads();
    const float g = lng[t], b = lnb[t];
    float vnew[NPB];
    #pragma unroll
    for (int n = 0; n < NPB; n++) {
        const float s = psum[0][n].x + psum[1][n].x;
        const float ss = psum[0][n].y + psum[1][n].y;
        const float mu = s * (1.f / HID);
        const float var = ss * (1.f / HID) - mu * mu;
        const float rs = rsqrtf(var + 1e-5f);
        const float hold = __half2float(((const __half*)&sh2[n * 64 + (t >> 1)])[t & 1]);
        const float v = fmaxf((acc[n] - mu) * rs * g + b, 0.f) + hold;
        vnew[n] = v;
        h[(size_t)(node0 + n) * HID + t] = v;
    }
    if (EMIT) {
        __syncthreads();
        #pragma unroll
        for (int n = 0; n < NPB; n++) {
            const float vx = __shfl_xor(vnew[n], 1);
            if (!(t & 1)) sh2[n * 64 + (t >> 1)] = packh2(vnew[n], vx);
        }
        __syncthreads();
        const unsigned* pkN = pkL + 2 * 16 * 128 * 4;
        float acc2[NPB];
        const float nbv = nb1[t];
        #pragma unroll
        for (int n = 0; n < NPB; n++) acc2[n] = nbv;
        for (int kk = 0; kk < 16; kk++) {
            const uint4 wn = *(const uint4*)(pkN + ((size_t)kk * 128 + t) * 4);
            #pragma unroll
            for (int n = 0; n < NPB; n++) {
                const uint4 ha = *(const uint4*)&sh2[n * 64 + kk * 4];
                acc2[n] = fdot2f(asH2(ha.x), asH2(wn.x), acc2[n]);
                acc2[n] = fdot2f(asH2(ha.y), asH2(wn.y), acc2[n]);
                acc2[n] = fdot2f(asH2(ha.z), asH2(wn.z), acc2[n]);
                acc2[n] = fdot2f(asH2(ha.w), asH2(wn.w), acc2[n]);
            }
        }
        __half* o = npart + (size_t)node0 * HID + t;
        #pragma unroll
        for (int n = 0; n < NPB; n++) o[n * HID] = __float2half(acc2[n]);
    }
}

// ---------------- fused pooling + readout (batch sorted -> segment scan) ----------------

__global__ __launch_bounds__(128) void pool_readout(const float* __restrict__ h,
                                                    const int* __restrict__ batch,
                                                    const float* __restrict__ w1,
                                                    const float* __restrict__ b1,
                                                    const float* __restrict__ w2,
                                                    const float* __restrict__ b2,
                                                    float* __restrict__ out) {
    __shared__ int sbe[2];
    __shared__ float g[2 * HID];
    __shared__ float red[2];
    const int t = threadIdx.x, gi = blockIdx.x;
    if (t < 2) {
        const int target = gi + t;
        int lo = 0, hi = N_NODES;
        while (lo < hi) { int m = (lo + hi) >> 1; if (batch[m] < target) lo = m + 1; else hi = m; }
        sbe[t] = lo;
    }
    __syncthreads();
    const int beg = sbe[0], end = sbe[1];
    float sum = 0.f, mx = -INFINITY;
    int n = beg;
    for (; n + 4 <= end; n += 4) {
        const float v0 = h[(size_t)(n + 0) * HID + t];
        const float v1 = h[(size_t)(n + 1) * HID + t];
        const float v2 = h[(size_t)(n + 2) * HID + t];
        const float v3 = h[(size_t)(n + 3) * HID + t];
        sum += v0 + v1 + v2 + v3;
        mx = fmaxf(mx, fmaxf(fmaxf(v0, v1), fmaxf(v2, v3)));
    }
    for (; n < end; n++) { const float v = h[(size_t)n * HID + t]; sum += v; mx = fmaxf(mx, v); }
    const float c = fmaxf((float)(end - beg), 1.f);
    g[t] = sum / c;
    g[HID + t] = mx;
    __syncthreads();
    float acc = b1[t];
    for (int k = 0; k < 2 * HID; k++) acc += g[k] * w1[k * HID + t];
    float s = fmaxf(acc, 0.f) * w2[t];
    s += __shfl_down(s, 32); s += __shfl_down(s, 16); s += __shfl_down(s, 8);
    s += __shfl_down(s, 4);  s += __shfl_down(s, 2);  s += __shfl_down(s, 1);
    if ((t & 63) == 0) red[t >> 6] = s;
    __syncthreads();
    if (t == 0) out[gi] = red[0] + red[1] + b2[0];
}

// ---------------- launch ----------------

extern "C" void kernel_launch(void* const* d_in, const int* in_sizes, int n_in,
                              void* d_out, int out_size, void* d_ws, size_t ws_size,
                              hipStream_t stream) {
    const float* x           = (const float*)d_in[0];
    const int*   edge_index  = (const int*)  d_in[1];
    const float* edge_attr   = (const float*)d_in[2];
    const int*   batch       = (const int*)  d_in[3];
    const float* node_proj_w = (const float*)d_in[4];
    const float* node_proj_b = (const float*)d_in[5];
    const float* msg_w1      = (const float*)d_in[6];
    const float* msg_b1      = (const float*)d_in[7];
    const float* msg_w2      = (const float*)d_in[8];
    const float* msg_b2      = (const float*)d_in[9];
    const float* upd_w       = (const float*)d_in[10];
    const float* upd_b       = (const float*)d_in[11];
    const float* ln_g        = (const float*)d_in[12];
    const float* ln_b        = (const float*)d_in[13];
    const float* ffn_w1      = (const float*)d_in[14];
    const float* ffn_b1      = (const float*)d_in[15];
    const float* ffn_w2      = (const float*)d_in[16];
    const float* ffn_b2      = (const float*)d_in[17];
    float* out = (float*)d_out;

    char* ws = (char*)d_ws;
    size_t off = 0;
    auto alloc = [&](size_t b) -> char* {
        char* p = ws + off;
        off = (off + b + 255) & ~(size_t)255;
        return p;
    };
    float*    h        = (float*)alloc((size_t)N_NODES * HID * 4);
    __half*   npart_h  = (__half*)alloc((size_t)N_NODES * HID * 2);
    float*    r        = (float*)alloc((size_t)N_NODES * HID * 4);
    float*    W2u_all  = (float*)alloc((size_t)N_LAYERS * HID * HID * 4);
    float*    b2u_all  = (float*)alloc((size_t)N_LAYERS * HID * 4);
    unsigned* w1epk    = (unsigned*)alloc((size_t)N_LAYERS * HID * 8 * 4);
    unsigned* pkU      = (unsigned*)alloc((size_t)9 * 16 * 128 * 4 * 4);
    int*      rowptr   = (int*)alloc((N_NODES + 1) * 4);
    int*      deg      = (int*)alloc((size_t)N_NODES * 4 * 2);      // deg + cursor contiguous
    int*      cursor   = deg + N_NODES;
    int*      csr_src  = (int*)alloc((size_t)N_EDGES * 4);
    __half*   eattr_h  = (__half*)alloc((size_t)N_EDGES * EDGE_DIM * 2);
    (void)in_sizes; (void)n_in; (void)out_size; (void)ws_size;

    // CSR build (per call; ws is re-poisoned each launch)
    hipMemsetAsync(deg, 0, (size_t)N_NODES * 4 * 2, stream);
    hist_kernel<<<(N_EDGES + 255) / 256, 256, 0, stream>>>(edge_index + N_EDGES, deg, N_EDGES);
    scan_kernel<<<1, 1024, 0, stream>>>(deg, rowptr);
    scatter_kernel<<<(N_EDGES + 255) / 256, 256, 0, stream>>>(edge_index, edge_attr, rowptr,
                                                              cursor, csr_src, eattr_h, N_EDGES);
    prep_w1e<<<N_LAYERS, 128, 0, stream>>>(msg_w1, w1epk);
    w2u_all<<<N_LAYERS * 129, 128, 0, stream>>>(msg_w2, msg_b2, upd_w, W2u_all, b2u_all);
    pack_upd<<<9, 128, 0, stream>>>(upd_w, W2u_all, msg_w1, pkU);
    // h = x @ node_proj_w + b ; npart(layer0) = h @ msg_w1[0][:128] + msg_b1[0]
    gemm_fused<<<N_NODES / 16, 128, 0, stream>>>(x, node_proj_w, node_proj_b,
                                                 msg_w1, msg_b1, h, npart_h);

    for (int l = 0; l < N_LAYERS; l++) {
        edge_aggr6<<<N_NODES / 4, 256, 0, stream>>>(npart_h, w1epk + (size_t)l * HID * 8,
                                                    eattr_h, rowptr, csr_src, r);
        const unsigned* pkL = pkU + (size_t)(l * 3) * 16 * 128 * 4;
        if (l + 1 < N_LAYERS)
            update_nodes2<true><<<N_NODES / 8, 128, 0, stream>>>(
                h, r, deg, pkL, upd_b + l * HID, b2u_all + l * HID,
                ln_g + l * HID, ln_b + l * HID, msg_b1 + (size_t)(l + 1) * HID, npart_h);
        else
            update_nodes2<false><<<N_NODES / 8, 128, 0, stream>>>(
                h, r, deg, pkL, upd_b + l * HID, b2u_all + l * HID,
                ln_g + l * HID, ln_b + l * HID, msg_b1, npart_h);
    }

    pool_readout<<<N_GRAPHS, 128, 0, stream>>>(h, batch, ffn_w1, ffn_b1, ffn_w2, ffn_b2, out);
}